// Round 3
// baseline (151.345 us; speedup 1.0000x reference)
//
#include <hip/hip_runtime.h>

#define BATCH 16
#define NN 1024
#define FF 128

typedef __attribute__((ext_vector_type(8))) short bf16x8;
typedef __attribute__((ext_vector_type(4))) float f32x4;

__device__ __forceinline__ unsigned short f2bf(float x) {
  unsigned u = __float_as_uint(x);
  u += 0x7fff + ((u >> 16) & 1);   // round-to-nearest-even
  return (unsigned short)(u >> 16);
}
__device__ __forceinline__ float bf2f(unsigned short b) {
  return __uint_as_float(((unsigned)b) << 16);
}
__device__ __forceinline__ bf16x8 cvt8(float4 a, float4 b) {
  bf16x8 r;
  r[0] = (short)f2bf(a.x); r[1] = (short)f2bf(a.y);
  r[2] = (short)f2bf(a.z); r[3] = (short)f2bf(a.w);
  r[4] = (short)f2bf(b.x); r[5] = (short)f2bf(b.y);
  r[6] = (short)f2bf(b.z); r[7] = (short)f2bf(b.w);
  return r;
}

// ---------------------------------------------------------------------------
// K1: deg[b,n] = 1 + sum_m A[b,n,m];  d = rsqrt(deg).  One wave per row.
// Tail blocks (>=4096) build Wt[g][f] = bf16(W[f][g]).
// ---------------------------------------------------------------------------
__global__ __launch_bounds__(256) void k_deg(const float* __restrict__ A,
                                             const float* __restrict__ W,
                                             float* __restrict__ d,
                                             unsigned short* __restrict__ Wt) {
  if (blockIdx.x >= 4096) {
    int id = (blockIdx.x - 4096) * 256 + threadIdx.x;
    int g = id >> 7, f = id & 127;
    Wt[g * 128 + f] = f2bf(W[f * 128 + g]);
    return;
  }
  int row  = blockIdx.x * 4 + (threadIdx.x >> 6);
  int lane = threadIdx.x & 63;
  const float4* Ar = (const float4*)(A + (size_t)row * NN);
  float s = 0.f;
#pragma unroll
  for (int i = 0; i < 4; ++i) {
    float4 v = Ar[lane + i * 64];
    s += (v.x + v.y) + (v.z + v.w);
  }
#pragma unroll
  for (int off = 32; off > 0; off >>= 1) s += __shfl_down(s, off, 64);
  if (lane == 0) d[row] = rsqrtf(s + 1.0f);
}

// ---------------------------------------------------------------------------
// K2: Yt[b][g][m] = bf16( d[b,m] * sum_f X[b,m,f] * W[f,g] )
// LDS-staged, single K-stage (K=128). Block: 64 m-rows x 128 g, 4 waves.
// XOR-swizzled LDS chunk layout: row r, 16-B chunk c stored at pos c^(r&15).
// ---------------------------------------------------------------------------
__global__ __launch_bounds__(256) void k_xw(const float* __restrict__ X,
                                            const unsigned short* __restrict__ Wt,
                                            const float* __restrict__ d,
                                            unsigned short* __restrict__ Yt) {
  __shared__ __align__(16) unsigned short Xs[64 * 128];
  __shared__ __align__(16) unsigned short Ws[128 * 128];
  __shared__ float dl[64];
  int t  = threadIdx.x;
  int b  = blockIdx.x >> 4;
  int m0 = (blockIdx.x & 15) * 64;

  // stage X (64x128 fp32 -> bf16, swizzled)
#pragma unroll
  for (int j = 0; j < 4; ++j) {
    int id = t + j * 256;
    int r = id >> 4, p = id & 15, c = p ^ (r & 15);
    const float* gp = X + ((size_t)(b * NN + m0 + r) * FF + c * 8);
    float4 v0 = *(const float4*)gp;
    float4 v1 = *(const float4*)(gp + 4);
    *(bf16x8*)&Xs[r * 128 + p * 8] = cvt8(v0, v1);
  }
  // stage W (128x128 bf16, swizzled)
#pragma unroll
  for (int j = 0; j < 8; ++j) {
    int id = t + j * 256;
    int g = id >> 4, p = id & 15, c = p ^ (g & 15);
    uint4 v = *(const uint4*)(Wt + g * 128 + c * 8);
    *(uint4*)&Ws[g * 128 + p * 8] = v;
  }
  if (t < 64) dl[t] = d[b * NN + m0 + t];
  __syncthreads();

  int wave = t >> 6, lane = t & 63, quad = lane >> 4, l16 = lane & 15;
  f32x4 acc[8];
#pragma unroll
  for (int ct = 0; ct < 8; ++ct) acc[ct] = (f32x4){0.f, 0.f, 0.f, 0.f};

#pragma unroll
  for (int ks = 0; ks < 4; ++ks) {
    int q = ks * 4 + quad;
    bf16x8 a = *(const bf16x8*)&Xs[(wave * 16 + l16) * 128 + (q ^ l16) * 8];
#pragma unroll
    for (int ct = 0; ct < 8; ++ct) {
      bf16x8 w = *(const bf16x8*)&Ws[(ct * 16 + l16) * 128 + (q ^ l16) * 8];
      acc[ct] = __builtin_amdgcn_mfma_f32_16x16x32_bf16(a, w, acc[ct], 0, 0, 0);
    }
  }

  // C/D: row(m) = quad*4+reg, col(g) = l16. Store transposed Yt[b][g][m].
  int mb = wave * 16 + quad * 4;
  float4 d4 = *(const float4*)&dl[mb];
#pragma unroll
  for (int ct = 0; ct < 8; ++ct) {
    int g = ct * 16 + l16;
    ushort4 p;
    p.x = f2bf(d4.x * acc[ct][0]);
    p.y = f2bf(d4.y * acc[ct][1]);
    p.z = f2bf(d4.z * acc[ct][2]);
    p.w = f2bf(d4.w * acc[ct][3]);
    *(ushort4*)(Yt + (size_t)(b * 128 + g) * NN + m0 + mb) = p;
  }
}

// ---------------------------------------------------------------------------
// K3: out[b,n,g] = d[n] * ( sum_m A[b,n,m]*Yt[b,g,m] + Yt[b,g,n] )
// Per-batch GEMM 1024x128x1024. Block tile 32n x 128g, BK=128, 8 stages,
// double-buffered swizzled LDS (A 2x8KB + Y 2x32KB = 80KB -> 2 blocks/CU).
// Grid 512 blocks x 4 waves; wave tile 16n x 64g.
// ---------------------------------------------------------------------------
__global__ __launch_bounds__(256, 2) void k_agg(const float* __restrict__ A,
                                                const unsigned short* __restrict__ Yt,
                                                const float* __restrict__ d,
                                                float* __restrict__ out) {
  __shared__ __align__(16) unsigned short As[2][32 * 128];
  __shared__ __align__(16) unsigned short Ys[2][128 * 128];
  int t  = threadIdx.x;
  int b  = blockIdx.x >> 5;
  int n0 = (blockIdx.x & 31) * 32;
  int wave = t >> 6, lane = t & 63, quad = lane >> 4, l16 = lane & 15;
  int wr = wave >> 1, wc = wave & 1;

  // staging descriptors (swizzled): LDS pos p holds global chunk c = p^(row&15)
  int rA[2], pA[2];
  const float* gA[2];
#pragma unroll
  for (int j = 0; j < 2; ++j) {
    int id = t + j * 256;
    rA[j] = id >> 4; pA[j] = id & 15;
    int c = pA[j] ^ (rA[j] & 15);
    gA[j] = A + ((size_t)(b * NN + n0 + rA[j]) * NN + c * 8);
  }
  int rY[8]; int pY = t & 15;
  const unsigned short* gY[8];
#pragma unroll
  for (int j = 0; j < 8; ++j) {
    rY[j] = (t >> 4) + j * 16;
    int c = pY ^ (rY[j] & 15);
    gY[j] = Yt + ((size_t)(b * 128 + rY[j]) * NN + c * 8);
  }

  f32x4 acc[4];
#pragma unroll
  for (int ct = 0; ct < 4; ++ct) acc[ct] = (f32x4){0.f, 0.f, 0.f, 0.f};

  // load + write stage 0
  float4 ra[2][2]; uint4 ry[8];
#pragma unroll
  for (int j = 0; j < 2; ++j) {
    ra[j][0] = *(const float4*)(gA[j]);
    ra[j][1] = *(const float4*)(gA[j] + 4);
  }
#pragma unroll
  for (int j = 0; j < 8; ++j) ry[j] = *(const uint4*)(gY[j]);
#pragma unroll
  for (int j = 0; j < 2; ++j)
    *(bf16x8*)&As[0][rA[j] * 128 + pA[j] * 8] = cvt8(ra[j][0], ra[j][1]);
#pragma unroll
  for (int j = 0; j < 8; ++j)
    *(uint4*)&Ys[0][rY[j] * 128 + pY * 8] = ry[j];
  __syncthreads();

#pragma unroll 2
  for (int s = 0; s < 8; ++s) {
    int cur = s & 1;
    if (s < 7) {                         // prefetch stage s+1 into regs
      int k0 = (s + 1) * 128;
#pragma unroll
      for (int j = 0; j < 2; ++j) {
        ra[j][0] = *(const float4*)(gA[j] + k0);
        ra[j][1] = *(const float4*)(gA[j] + k0 + 4);
      }
#pragma unroll
      for (int j = 0; j < 8; ++j) ry[j] = *(const uint4*)(gY[j] + k0);
    }
    // compute stage s (16 MFMAs/wave)
#pragma unroll
    for (int ks = 0; ks < 4; ++ks) {
      int q = ks * 4 + quad;
      bf16x8 a = *(const bf16x8*)&As[cur][(wr * 16 + l16) * 128 + (q ^ l16) * 8];
#pragma unroll
      for (int ct = 0; ct < 4; ++ct) {
        bf16x8 y = *(const bf16x8*)&Ys[cur][(wc * 64 + ct * 16 + l16) * 128 + (q ^ l16) * 8];
        acc[ct] = __builtin_amdgcn_mfma_f32_16x16x32_bf16(a, y, acc[ct], 0, 0, 0);
      }
    }
    if (s < 7) {                         // convert + write stage s+1
      int nxt = cur ^ 1;
#pragma unroll
      for (int j = 0; j < 2; ++j)
        *(bf16x8*)&As[nxt][rA[j] * 128 + pA[j] * 8] = cvt8(ra[j][0], ra[j][1]);
#pragma unroll
      for (int j = 0; j < 8; ++j)
        *(uint4*)&Ys[nxt][rY[j] * 128 + pY * 8] = ry[j];
    }
    __syncthreads();
  }

  // epilogue: out[n,g] = d[n]*(acc + Yt[g][n]); C/D: row = quad*4+reg, col = l16
  int nb = n0 + wr * 16 + quad * 4;
  float4 d4 = *(const float4*)(d + b * NN + nb);
#pragma unroll
  for (int ct = 0; ct < 4; ++ct) {
    int g = wc * 64 + ct * 16 + l16;
    ushort4 yv = *(const ushort4*)(Yt + (size_t)(b * 128 + g) * NN + nb);
    float* op = out + ((size_t)(b * NN + nb) * FF + g);
    op[0 * FF] = d4.x * (acc[ct][0] + bf2f(yv.x));
    op[1 * FF] = d4.y * (acc[ct][1] + bf2f(yv.y));
    op[2 * FF] = d4.z * (acc[ct][2] + bf2f(yv.z));
    op[3 * FF] = d4.w * (acc[ct][3] + bf2f(yv.w));
  }
}

// ---------------------------------------------------------------------------
extern "C" void kernel_launch(void* const* d_in, const int* in_sizes, int n_in,
                              void* d_out, int out_size, void* d_ws, size_t ws_size,
                              hipStream_t stream) {
  const float* X = (const float*)d_in[0];  // [16,1024,128]
  const float* A = (const float*)d_in[1];  // [16,1024,1024]
  const float* W = (const float*)d_in[2];  // [128,128]
  float* out = (float*)d_out;              // [16,1024,128]

  char* ws = (char*)d_ws;
  float*          dinv = (float*)ws;                              // 64 KB
  unsigned short* Wt   = (unsigned short*)(ws + 65536);           // 32 KB
  unsigned short* Yt   = (unsigned short*)(ws + 65536 + 32768);   // 4 MB  [b][g][m]

  k_deg<<<dim3(4096 + 64), dim3(256), 0, stream>>>(A, W, dinv, Wt);
  k_xw <<<dim3(256),       dim3(256), 0, stream>>>(X, Wt, dinv, Yt);
  k_agg<<<dim3(512),       dim3(256), 0, stream>>>(A, Yt, dinv, out);
}

// Round 4
// 120.112 us; speedup vs baseline: 1.2600x; 1.2600x over previous
//
#include <hip/hip_runtime.h>

#define NN 1024
#define FF 128

typedef __attribute__((ext_vector_type(8))) short bf16x8;
typedef __attribute__((ext_vector_type(4))) float f32x4;

__device__ __forceinline__ unsigned short f2bf(float x) {
  unsigned u = __float_as_uint(x);
  u += 0x7fff + ((u >> 16) & 1);   // round-to-nearest-even
  return (unsigned short)(u >> 16);
}
__device__ __forceinline__ float bf2f(unsigned short b) {
  return __uint_as_float(((unsigned)b) << 16);
}
__device__ __forceinline__ bf16x8 cvt8(float4 a, float4 b) {
  bf16x8 r;
  r[0] = (short)f2bf(a.x); r[1] = (short)f2bf(a.y);
  r[2] = (short)f2bf(a.z); r[3] = (short)f2bf(a.w);
  r[4] = (short)f2bf(b.x); r[5] = (short)f2bf(b.y);
  r[6] = (short)f2bf(b.z); r[7] = (short)f2bf(b.w);
  return r;
}

// async global->LDS, 16B per lane. LDS dest = wave-uniform base + lane*16.
__device__ __forceinline__ void gl_lds16(const void* g, void* l) {
  __builtin_amdgcn_global_load_lds(
      (const __attribute__((address_space(1))) unsigned*)g,
      (__attribute__((address_space(3))) unsigned*)l, 16, 0, 0);
}

// ---------------------------------------------------------------------------
// K1: deg[b,n] = 1 + sum_m A[b,n,m]; d = rsqrt(deg). One wave per row.
// Also emits Abf = bf16(A) (hot-loop conversion hoisted out of k_agg).
// Tail blocks (>=4096) build Wt[g][f] = bf16(W[f][g]).
// ---------------------------------------------------------------------------
__global__ __launch_bounds__(256) void k_deg(const float* __restrict__ A,
                                             const float* __restrict__ W,
                                             float* __restrict__ d,
                                             unsigned short* __restrict__ Wt,
                                             unsigned short* __restrict__ Abf) {
  if (blockIdx.x >= 4096) {
    int id = (blockIdx.x - 4096) * 256 + threadIdx.x;
    int g = id >> 7, f = id & 127;
    Wt[g * 128 + f] = f2bf(W[f * 128 + g]);
    return;
  }
  int row  = blockIdx.x * 4 + (threadIdx.x >> 6);
  int lane = threadIdx.x & 63;
  const float4* Ar = (const float4*)(A + (size_t)row * NN);
  unsigned short* Br = Abf + (size_t)row * NN;
  float s = 0.f;
#pragma unroll
  for (int i = 0; i < 4; ++i) {
    float4 v = Ar[lane + i * 64];
    ushort4 p; p.x = f2bf(v.x); p.y = f2bf(v.y); p.z = f2bf(v.z); p.w = f2bf(v.w);
    *(ushort4*)(Br + (lane + i * 64) * 4) = p;
    s += (v.x + v.y) + (v.z + v.w);
  }
#pragma unroll
  for (int off = 32; off > 0; off >>= 1) s += __shfl_down(s, off, 64);
  if (lane == 0) d[row] = rsqrtf(s + 1.0f);
}

// ---------------------------------------------------------------------------
// K2: Yt[b][g][m] = bf16( d[b,m] * sum_f X[b,m,f] * W[f,g] )
// LDS-staged, single K-stage (K=128). Block: 64 m-rows x 128 g, 4 waves.
// XOR-swizzled LDS chunk layout: row r, 16-B chunk c stored at pos c^(r&15).
// ---------------------------------------------------------------------------
__global__ __launch_bounds__(256) void k_xw(const float* __restrict__ X,
                                            const unsigned short* __restrict__ Wt,
                                            const float* __restrict__ d,
                                            unsigned short* __restrict__ Yt) {
  __shared__ __align__(16) unsigned short Xs[64 * 128];
  __shared__ __align__(16) unsigned short Ws[128 * 128];
  __shared__ float dl[64];
  int t  = threadIdx.x;
  int b  = blockIdx.x >> 4;
  int m0 = (blockIdx.x & 15) * 64;

#pragma unroll
  for (int j = 0; j < 4; ++j) {
    int id = t + j * 256;
    int r = id >> 4, p = id & 15, c = p ^ (r & 15);
    const float* gp = X + ((size_t)(b * NN + m0 + r) * FF + c * 8);
    float4 v0 = *(const float4*)gp;
    float4 v1 = *(const float4*)(gp + 4);
    *(bf16x8*)&Xs[r * 128 + p * 8] = cvt8(v0, v1);
  }
#pragma unroll
  for (int j = 0; j < 8; ++j) {
    int id = t + j * 256;
    int g = id >> 4, p = id & 15, c = p ^ (g & 15);
    uint4 v = *(const uint4*)(Wt + g * 128 + c * 8);
    *(uint4*)&Ws[g * 128 + p * 8] = v;
  }
  if (t < 64) dl[t] = d[b * NN + m0 + t];
  __syncthreads();

  int wave = t >> 6, lane = t & 63, quad = lane >> 4, l16 = lane & 15;
  f32x4 acc[8];
#pragma unroll
  for (int ct = 0; ct < 8; ++ct) acc[ct] = (f32x4){0.f, 0.f, 0.f, 0.f};

#pragma unroll
  for (int ks = 0; ks < 4; ++ks) {
    int q = ks * 4 + quad;
    bf16x8 a = *(const bf16x8*)&Xs[(wave * 16 + l16) * 128 + (q ^ l16) * 8];
#pragma unroll
    for (int ct = 0; ct < 8; ++ct) {
      bf16x8 w = *(const bf16x8*)&Ws[(ct * 16 + l16) * 128 + (q ^ l16) * 8];
      acc[ct] = __builtin_amdgcn_mfma_f32_16x16x32_bf16(a, w, acc[ct], 0, 0, 0);
    }
  }

  int mb = wave * 16 + quad * 4;
  float4 d4 = *(const float4*)&dl[mb];
#pragma unroll
  for (int ct = 0; ct < 8; ++ct) {
    int g = ct * 16 + l16;
    ushort4 p;
    p.x = f2bf(d4.x * acc[ct][0]);
    p.y = f2bf(d4.y * acc[ct][1]);
    p.z = f2bf(d4.z * acc[ct][2]);
    p.w = f2bf(d4.w * acc[ct][3]);
    *(ushort4*)(Yt + (size_t)(b * 128 + g) * NN + m0 + mb) = p;
  }
}

// ---------------------------------------------------------------------------
// K3: out[b,n,g] = d[n] * ( sum_m Abf[b,n,m]*Yt[b,g,m] + Yt[b,g,n] )
// Per-batch GEMM 1024x128x1024. BM=32, BN=128, BK=128, 8 stages.
// Single 40KB LDS buffer staged ONLY via global_load_lds (no staging VGPRs,
// no ds_writes, no spills). XOR swizzle applied on the per-lane global source
// address so fragment ds_read_b128 is 2-way/free. Grid 512 -> 2 blocks/CU;
// resident blocks overlap each other's barrier drains.
// ---------------------------------------------------------------------------
__global__ __launch_bounds__(256, 2) void k_agg(const unsigned short* __restrict__ Abf,
                                                const unsigned short* __restrict__ Yt,
                                                const float* __restrict__ d,
                                                float* __restrict__ out) {
  __shared__ __align__(16) unsigned short As[32 * 128];
  __shared__ __align__(16) unsigned short Ys[128 * 128];
  int t  = threadIdx.x;
  int b  = blockIdx.x >> 5;
  int n0 = (blockIdx.x & 31) * 32;
  int wave = t >> 6, lane = t & 63, quad = lane >> 4, l16 = lane & 15;
  int wr = wave >> 1, wc = wave & 1;
  int rl = lane >> 4, pl = lane & 15;   // staging: row-within-4, chunk pos

  const unsigned short* Ab = Abf + (size_t)(b * NN + n0) * NN;
  const unsigned short* Yb = Yt + (size_t)b * 128 * NN;

  auto issue = [&](int k0) {
#pragma unroll
    for (int j = 0; j < 2; ++j) {       // A: 32 rows x 256B
      int r0 = wave * 8 + j * 4;
      int r  = r0 + rl;
      int c  = pl ^ (r & 15);
      gl_lds16(Ab + ((size_t)r * NN + k0 + c * 8), &As[r0 * 128]);
    }
#pragma unroll
    for (int j = 0; j < 8; ++j) {       // Y: 128 rows x 256B
      int r0 = wave * 32 + j * 4;
      int r  = r0 + rl;
      int c  = pl ^ (r & 15);
      gl_lds16(Yb + ((size_t)r * NN + k0 + c * 8), &Ys[r0 * 128]);
    }
  };

  f32x4 acc[4];
#pragma unroll
  for (int ct = 0; ct < 4; ++ct) acc[ct] = (f32x4){0.f, 0.f, 0.f, 0.f};

  issue(0);
  for (int s = 0; s < 8; ++s) {
    __syncthreads();                    // vmcnt(0) drain: stage-s data in LDS
#pragma unroll
    for (int ks = 0; ks < 4; ++ks) {
      int cq = ks * 4 + quad;
      bf16x8 a = *(const bf16x8*)&As[(wr * 16 + l16) * 128 + (cq ^ l16) * 8];
#pragma unroll
      for (int ct = 0; ct < 4; ++ct) {
        bf16x8 y = *(const bf16x8*)&Ys[(wc * 64 + ct * 16 + l16) * 128 + (cq ^ l16) * 8];
        acc[ct] = __builtin_amdgcn_mfma_f32_16x16x32_bf16(a, y, acc[ct], 0, 0, 0);
      }
    }
    __syncthreads();                    // all waves done reading stage s
    if (s < 7) issue((s + 1) * 128);
  }

  // epilogue: out[n,g] = d[n]*(acc + Yt[g][n]); C/D: row = quad*4+reg, col = l16
  int nb = n0 + wr * 16 + quad * 4;
  float4 d4 = *(const float4*)(d + b * NN + nb);
#pragma unroll
  for (int ct = 0; ct < 4; ++ct) {
    int g = wc * 64 + ct * 16 + l16;
    ushort4 yv = *(const ushort4*)(Yt + (size_t)(b * 128 + g) * NN + nb);
    float* op = out + ((size_t)(b * NN + nb) * FF + g);
    op[0 * FF] = d4.x * (acc[ct][0] + bf2f(yv.x));
    op[1 * FF] = d4.y * (acc[ct][1] + bf2f(yv.y));
    op[2 * FF] = d4.z * (acc[ct][2] + bf2f(yv.z));
    op[3 * FF] = d4.w * (acc[ct][3] + bf2f(yv.w));
  }
}

// ---------------------------------------------------------------------------
extern "C" void kernel_launch(void* const* d_in, const int* in_sizes, int n_in,
                              void* d_out, int out_size, void* d_ws, size_t ws_size,
                              hipStream_t stream) {
  const float* X = (const float*)d_in[0];  // [16,1024,128]
  const float* A = (const float*)d_in[1];  // [16,1024,1024]
  const float* W = (const float*)d_in[2];  // [128,128]
  float* out = (float*)d_out;              // [16,1024,128]

  char* ws = (char*)d_ws;
  float*          dinv = (float*)ws;                                    // 64 KB
  unsigned short* Wt   = (unsigned short*)(ws + 65536);                 // 32 KB
  unsigned short* Yt   = (unsigned short*)(ws + 98304);                 // 4 MB [b][g][m]
  unsigned short* Abf  = (unsigned short*)(ws + 98304 + 4194304);       // 32 MB bf16(A)

  k_deg<<<dim3(4096 + 64), dim3(256), 0, stream>>>(A, W, dinv, Wt, Abf);
  k_xw <<<dim3(256),       dim3(256), 0, stream>>>(X, Wt, dinv, Yt);
  k_agg<<<dim3(512),       dim3(256), 0, stream>>>(Abf, Yt, dinv, out);
}